// Round 15
// baseline (149.023 us; speedup 1.0000x reference)
//
#include <hip/hip_runtime.h>
#include <hip/hip_fp16.h>
#include <math.h>

// ---------------------------------------------------------------------------
// GCN 2-layer, CSR-gather, fp16 storage + fp16 gather math:
//   rank[e] = atomicAdd(degi[dst[e]],1)   (4 edges/thread ILP, ∥ gemm1 A)
//   rowstart = exscan(degi); dinv = rsqrt(degi+1)
//   csr[rowstart[t]+rank[e]] = (src, half2(nrm))  (fill, ∥ gemm1 B)
//   h1(fp16) = x @ W1  -- MFMA 16x16x32_f16, A-frags AND B-frags direct from
//                         global (Wt pre-transposed fp16, 16KB, L1-resident);
//                         NO LDS, NO syncthreads in the tile.
//   out1(fp16) = relu(gather(h1) + self + b1)
//   out = log_softmax((gather(out1)+self) @ W2 + b2)  -- gather fused into GEMM2
// ---------------------------------------------------------------------------

typedef _Float16 f16x8 __attribute__((ext_vector_type(8)));
typedef float    f32x4 __attribute__((ext_vector_type(4)));

// blocks [0,NZ): zero degi; block NZ: transpose W1 -> Wt fp16 [64][128]
__global__ void prep_kernel(int* __restrict__ degi, int n,
                            const float* __restrict__ W, _Float16* __restrict__ Wt,
                            int NZ) {
    int b = blockIdx.x;
    int t = threadIdx.x;
    if (b < NZ) {
        int i = b * 256 + t;
        if (i < n) degi[i] = 0;
    } else {
        for (int i = t; i < 8192; i += 256) {
            int k = i >> 6, nn = i & 63;
            Wt[nn * 128 + k] = (_Float16)W[(size_t)k * 64 + nn];
        }
    }
}

// ---- gemm1 tile body (LDS-free): H[tile*64..+64, 0..64](fp16) = X @ W1 ----
static __device__ __forceinline__ void gemm1_tile(const float* __restrict__ X,
                                                  const _Float16* __restrict__ Wt,
                                                  _Float16* __restrict__ H, int n,
                                                  int tile) {
    int t = threadIdx.x;
    int rowbase = tile * 64;
    int w = t >> 6;
    int l = t & 63;
    int lr = l & 15;            // row-within-tile for A / col for B,D
    int lk = l >> 4;            // k-subchunk 0..3
    int arow = rowbase + 16 * w + lr;
    int ar = arow < n ? arow : n - 1;

    f16x8 a[4];
#pragma unroll
    for (int kc = 0; kc < 4; ++kc) {
        const float* xp = X + (size_t)ar * 128 + kc * 32 + lk * 8;
        float4 v0 = *reinterpret_cast<const float4*>(xp);
        float4 v1 = *reinterpret_cast<const float4*>(xp + 4);
        f16x8 hv = { (_Float16)v0.x, (_Float16)v0.y, (_Float16)v0.z, (_Float16)v0.w,
                     (_Float16)v1.x, (_Float16)v1.y, (_Float16)v1.z, (_Float16)v1.w };
        a[kc] = hv;
    }

    f32x4 acc[4] = {};
#pragma unroll
    for (int nt = 0; nt < 4; ++nt) {
        int nrow = 16 * nt + lr;
#pragma unroll
        for (int kc = 0; kc < 4; ++kc) {
            f16x8 b = *reinterpret_cast<const f16x8*>(&Wt[nrow * 128 + kc * 32 + lk * 8]);
            acc[nt] = __builtin_amdgcn_mfma_f32_16x16x32_f16(a[kc], b, acc[nt], 0, 0, 0);
        }
    }
    // D: col = lane&15, row = (lane>>4)*4 + reg
#pragma unroll
    for (int nt = 0; nt < 4; ++nt) {
#pragma unroll
        for (int r = 0; r < 4; ++r) {
            int grow = rowbase + 16 * w + lk * 4 + r;
            if (grow < n) H[(size_t)grow * 64 + nt * 16 + lr] = (_Float16)acc[nt][r];
        }
    }
}

// ---- FAT K2: deg_rank 4-edge-ILP (blocks < nDeg) ∥ gemm1 tiles [0,tilesA) ----
__global__ __launch_bounds__(256) void degrank_gemm1_kernel(
        const int* __restrict__ dst, int* __restrict__ degi, int* __restrict__ rank, int E,
        const float* __restrict__ X, const _Float16* __restrict__ Wt,
        _Float16* __restrict__ H, int n, int nDeg) {
    int b = blockIdx.x;
    if (b < nDeg) {
        int base = b * 1024 + threadIdx.x;
        int d[4]; bool v[4];
#pragma unroll
        for (int u = 0; u < 4; ++u) {
            int e = base + u * 256;
            v[u] = e < E;
            d[u] = v[u] ? dst[e] : 0;
        }
        int r[4];
#pragma unroll
        for (int u = 0; u < 4; ++u)
            if (v[u]) r[u] = atomicAdd(&degi[d[u]], 1);   // 4 outstanding atomics
#pragma unroll
        for (int u = 0; u < 4; ++u)
            if (v[u]) rank[base + u * 256] = r[u];
    } else {
        gemm1_tile(X, Wt, H, n, b - nDeg);
    }
}

// ---- FAT K5: fill (blocks < nFill) ∥ gemm1 tiles [tilesA, ntiles) ----
__global__ __launch_bounds__(256) void fill_gemm1_kernel(
        const int* __restrict__ src, const int* __restrict__ dst,
        const int* __restrict__ rank, const float* __restrict__ dinv,
        const int* __restrict__ rowstart, int2* __restrict__ csr, int E,
        const float* __restrict__ X, const _Float16* __restrict__ Wt,
        _Float16* __restrict__ H, int n, int nFill, int tileOff) {
    int b = blockIdx.x;
    if (b < nFill) {
        int e = b * 256 + threadIdx.x;
        if (e >= E) return;
        int s = src[e], t = dst[e];
        float nrm = dinv[s] * dinv[t];
        unsigned short us = __half_as_ushort(__float2half_rn(nrm));
        int packed = (int)(((unsigned)us << 16) | us);
        int pos = rowstart[t] + rank[e];
        csr[pos] = make_int2(s, packed);
    } else {
        gemm1_tile(X, Wt, H, n, b - nFill + tileOff);
    }
}

// ---- block sums of degi (1024 items / block) ----
__global__ __launch_bounds__(256) void blocksum_kernel(const int* __restrict__ degi,
                                                       int* __restrict__ partial, int n) {
    __shared__ int sm[256];
    int t = threadIdx.x;
    int base = blockIdx.x * 1024 + t * 4;
    int s = 0;
#pragma unroll
    for (int j = 0; j < 4; ++j) { int i = base + j; if (i < n) s += degi[i]; }
    sm[t] = s;
    __syncthreads();
    for (int off = 128; off > 0; off >>= 1) {
        if (t < off) sm[t] += sm[t + off];
        __syncthreads();
    }
    if (t == 0) partial[blockIdx.x] = sm[0];
}

// rowstart = exscan(degi); partial-scan fused; degi <- rsqrt(degi+1) in place
__global__ __launch_bounds__(256) void offsets_kernel(int* __restrict__ degi,
                                                      const int* __restrict__ partial,
                                                      int* __restrict__ rowstart,
                                                      int n, int nb) {
    __shared__ int sm[256];
    __shared__ int pbase_s;
    int t = threadIdx.x;
    int pv = (t < nb) ? partial[t] : 0;
    sm[t] = pv;
    __syncthreads();
    for (int off = 1; off < 256; off <<= 1) {
        int x = (t >= off) ? sm[t - off] : 0;
        __syncthreads();
        sm[t] += x;
        __syncthreads();
    }
    if (t == 0) pbase_s = (blockIdx.x > 0) ? sm[blockIdx.x - 1] : 0;
    __syncthreads();
    int pbase = pbase_s;
    __syncthreads();   // sm about to be reused

    int base = blockIdx.x * 1024 + t * 4;
    int v[4]; int s = 0;
#pragma unroll
    for (int j = 0; j < 4; ++j) { v[j] = (base + j < n) ? degi[base + j] : 0; s += v[j]; }
    sm[t] = s;
    __syncthreads();
    for (int off = 1; off < 256; off <<= 1) {
        int x = (t >= off) ? sm[t - off] : 0;
        __syncthreads();
        sm[t] += x;
        __syncthreads();
    }
    int run = pbase + (sm[t] - s);
#pragma unroll
    for (int j = 0; j < 4; ++j) {
        if (base + j < n) {
            rowstart[base + j] = run; run += v[j];
            ((float*)degi)[base + j] = rsqrtf((float)v[j] + 1.0f);  // +1 self-loop
        }
    }
}

// branch-free half2 ReLU
static __device__ __forceinline__ __half2 relu_h2(__half2 v) {
    unsigned u = *reinterpret_cast<unsigned*>(&v);
    unsigned neg = (u >> 15) & 0x00010001u;
    u &= ~(neg * 0xFFFFu);
    return *reinterpret_cast<__half2*>(&u);
}

// ---- gather over 64-feature fp16 rows: 8 lanes/node, 8 nodes/wave ----
template <bool RELU, bool BIAS>
__global__ __launch_bounds__(256) void gather64h_kernel(const __half* __restrict__ Hh,
                                                        const int2* __restrict__ csr,
                                                        const int* __restrict__ rowstart,
                                                        const float* __restrict__ dinv,
                                                        const float* __restrict__ b,
                                                        __half* __restrict__ Oh, int n, int E) {
    int gt = blockIdx.x * blockDim.x + threadIdx.x;
    int node = gt >> 3;
    if (node >= n) return;
    int fl = gt & 7;
    const float4* H4 = reinterpret_cast<const float4*>(Hh);
    int rs = rowstart[node];
    int re = (node + 1 < n) ? rowstart[node + 1] : E;
    __half2 acc[4];
#pragma unroll
    for (int q = 0; q < 4; ++q) acc[q] = __float2half2_rn(0.0f);

    int e = rs;
    while (__any(e < re)) {
        int srcrow[4]; __half2 nh[4]; float4 raw[4];
#pragma unroll
        for (int u = 0; u < 4; ++u) {
            int ee = e + u;
            bool valid = ee < re;
            int2 c = csr[valid ? ee : rs];
            srcrow[u] = valid ? c.x : 0;
            int ni = valid ? c.y : 0;
            nh[u] = *reinterpret_cast<__half2*>(&ni);
        }
#pragma unroll
        for (int u = 0; u < 4; ++u)
            raw[u] = H4[srcrow[u] * 8 + fl];
#pragma unroll
        for (int u = 0; u < 4; ++u) {
            const __half2* hp = reinterpret_cast<const __half2*>(&raw[u]);
#pragma unroll
            for (int q = 0; q < 4; ++q)
                acc[q] = __hfma2(hp[q], nh[u], acc[q]);
        }
        e += 4;
    }
    {
        float di = dinv[node];
        __half2 d2 = __float2half2_rn(di * di);
        float4 raw = H4[node * 8 + fl];
        const __half2* hp = reinterpret_cast<const __half2*>(&raw);
#pragma unroll
        for (int q = 0; q < 4; ++q) acc[q] = __hfma2(hp[q], d2, acc[q]);
    }
    if (BIAS) {
        float4 b0 = reinterpret_cast<const float4*>(b)[fl * 2];
        float4 b1 = reinterpret_cast<const float4*>(b)[fl * 2 + 1];
        acc[0] = __hadd2(acc[0], __float22half2_rn(make_float2(b0.x, b0.y)));
        acc[1] = __hadd2(acc[1], __float22half2_rn(make_float2(b0.z, b0.w)));
        acc[2] = __hadd2(acc[2], __float22half2_rn(make_float2(b1.x, b1.y)));
        acc[3] = __hadd2(acc[3], __float22half2_rn(make_float2(b1.z, b1.w)));
    }
    if (RELU) {
#pragma unroll
        for (int q = 0; q < 4; ++q) acc[q] = relu_h2(acc[q]);
    }
    float4 o;
    __half2* op = reinterpret_cast<__half2*>(&o);
#pragma unroll
    for (int q = 0; q < 4; ++q) op[q] = acc[q];
    *reinterpret_cast<float4*>(Oh + (size_t)node * 64 + fl * 8) = o;
}

// ---- FUSED: agg2 = gather(out1)+self (LDS, fp32) -> log_softmax(agg2@W2+b2) ----
__global__ __launch_bounds__(256) void gather_gemm2_softmax(
        const __half* __restrict__ Hh, const int2* __restrict__ csr,
        const int* __restrict__ rowstart, const float* __restrict__ dinv,
        const float* __restrict__ W, const float* __restrict__ b,
        float* __restrict__ out, int n, int E) {
    constexpr int BM = 64, K = 64, C = 40, XP = 68, HP = 41;
    __shared__ float Xs[BM * XP];
    __shared__ float Ws[K * C];
    __shared__ float bs[C];
    __shared__ float rowm[BM], rowls[BM];
    int t = threadIdx.x;
    int rowbase = blockIdx.x * BM;

    for (int i = t; i < K * C / 4; i += 256)
        ((float4*)Ws)[i] = ((const float4*)W)[i];
    if (t < C) bs[t] = b[t];

    int team = t >> 3, fl = t & 7;
    const float4* H4 = reinterpret_cast<const float4*>(Hh);
#pragma unroll
    for (int pass = 0; pass < 2; ++pass) {
        int lrow = team + pass * 32;
        int node = rowbase + lrow;
        __half2 acc[4];
#pragma unroll
        for (int q = 0; q < 4; ++q) acc[q] = __float2half2_rn(0.0f);
        if (node < n) {
            int rs = rowstart[node];
            int re = (node + 1 < n) ? rowstart[node + 1] : E;
            int e = rs;
            while (__any(e < re)) {
                int srcrow[4]; __half2 nh[4]; float4 raw[4];
#pragma unroll
                for (int u = 0; u < 4; ++u) {
                    int ee = e + u;
                    bool valid = ee < re;
                    int2 c = csr[valid ? ee : rs];
                    srcrow[u] = valid ? c.x : 0;
                    int ni = valid ? c.y : 0;
                    nh[u] = *reinterpret_cast<__half2*>(&ni);
                }
#pragma unroll
                for (int u = 0; u < 4; ++u)
                    raw[u] = H4[srcrow[u] * 8 + fl];
#pragma unroll
                for (int u = 0; u < 4; ++u) {
                    const __half2* hp = reinterpret_cast<const __half2*>(&raw[u]);
#pragma unroll
                    for (int q = 0; q < 4; ++q)
                        acc[q] = __hfma2(hp[q], nh[u], acc[q]);
                }
                e += 4;
            }
            float di = dinv[node];
            __half2 d2 = __float2half2_rn(di * di);
            float4 raw = H4[node * 8 + fl];
            const __half2* hp = reinterpret_cast<const __half2*>(&raw);
#pragma unroll
            for (int q = 0; q < 4; ++q) acc[q] = __hfma2(hp[q], d2, acc[q]);
        }
        float* dp = &Xs[lrow * XP + fl * 8];
        float2 f0 = __half22float2(acc[0]), f1 = __half22float2(acc[1]);
        float2 f2 = __half22float2(acc[2]), f3 = __half22float2(acc[3]);
        *reinterpret_cast<float4*>(dp)     = make_float4(f0.x, f0.y, f1.x, f1.y);
        *reinterpret_cast<float4*>(dp + 4) = make_float4(f2.x, f2.y, f3.x, f3.y);
    }
    __syncthreads();

    int tx = t % (C / 4);
    int ty = t / (C / 4);
    bool active = ty < BM / 4;
    float acc[4][4] = {};
    if (active) {
#pragma unroll
        for (int k0 = 0; k0 < K; k0 += 4) {
            float4 xq[4], wq[4];
#pragma unroll
            for (int i = 0; i < 4; ++i)
                xq[i] = *reinterpret_cast<const float4*>(&Xs[(ty * 4 + i) * XP + k0]);
#pragma unroll
            for (int j = 0; j < 4; ++j)
                wq[j] = *reinterpret_cast<const float4*>(&Ws[(k0 + j) * C + tx * 4]);
#pragma unroll
            for (int i = 0; i < 4; ++i) {
                const float* xa = reinterpret_cast<const float*>(&xq[i]);
#pragma unroll
                for (int j = 0; j < 4; ++j) {
                    const float* wb = reinterpret_cast<const float*>(&wq[j]);
                    acc[i][0] += xa[j] * wb[0];
                    acc[i][1] += xa[j] * wb[1];
                    acc[i][2] += xa[j] * wb[2];
                    acc[i][3] += xa[j] * wb[3];
                }
            }
        }
    }
    __syncthreads();
    float* Hs = Xs;
    if (active) {
#pragma unroll
        for (int i = 0; i < 4; ++i) {
            int r = ty * 4 + i;
#pragma unroll
            for (int j = 0; j < 4; ++j)
                Hs[r * HP + tx * 4 + j] = acc[i][j] + bs[tx * 4 + j];
        }
    }
    __syncthreads();
    if (t < BM) {
        float m = -INFINITY;
        for (int j = 0; j < C; ++j) m = fmaxf(m, Hs[t * HP + j]);
        float s = 0.f;
        for (int j = 0; j < C; ++j) s += __expf(Hs[t * HP + j] - m);
        rowm[t] = m; rowls[t] = __logf(s);
    }
    __syncthreads();
    for (int idx = t; idx < BM * C; idx += 256) {
        int r = idx / C, c = idx - r * C;
        int gr = rowbase + r;
        if (gr < n) out[(size_t)gr * C + c] = Hs[r * HP + c] - rowm[r] - rowls[r];
    }
}

extern "C" void kernel_launch(void* const* d_in, const int* in_sizes, int n_in,
                              void* d_out, int out_size, void* d_ws, size_t ws_size,
                              hipStream_t stream) {
    const float* x  = (const float*)d_in[0];
    const int*   ei = (const int*)d_in[1];
    const float* W1 = (const float*)d_in[2];
    const float* b1 = (const float*)d_in[3];
    const float* W2 = (const float*)d_in[4];
    const float* b2 = (const float*)d_in[5];
    float* out = (float*)d_out;

    const int n = in_sizes[0] / 128;   // 100000
    const int E = in_sizes[1] / 2;     // 800000
    const int* src = ei;
    const int* dst = ei + E;

    auto al = [](size_t v) { return (v + 255) & ~(size_t)255; };
    float* ws = (float*)d_ws;
    size_t o_deg  = 0;                          // n ints -> dinv floats in place
    size_t o_cnt  = al(n);                      // n ints (rowstart)
    size_t o_part = o_cnt + al(n);              // <=256 ints
    size_t o_wt   = o_part + 1024;              // 8192 halves (Wt) = 4096 floats
    size_t o_rank = o_wt + 4096;                // E ints
    size_t o_csr  = o_rank + al(E);             // E int2
    size_t o_h1   = o_csr + al((size_t)2 * E);  // n*64 halves
    size_t o_out1 = o_h1 + al((size_t)n * 32);  // n*64 halves

    int*      degi     = (int*)(ws + o_deg);
    float*    dinv     = (float*)(ws + o_deg);
    int*      rowstart = (int*)(ws + o_cnt);
    int*      partial  = (int*)(ws + o_part);
    _Float16* Wt       = (_Float16*)(ws + o_wt);
    int*      rank     = (int*)(ws + o_rank);
    int2*     csr      = (int2*)(ws + o_csr);
    __half*   h1       = (__half*)(ws + o_h1);
    __half*   out1     = (__half*)(ws + o_out1);

    const int NB = (n + 1023) / 1024;
    const int NZ = (n + 255) / 256;              // zero blocks
    const int nDeg   = (E + 1023) / 1024;        // 782 (4 edges/thread)
    const int nFill  = (E + 255) / 256;          // 3125
    const int ntiles = (n + 63) / 64;            // 1563
    const int tilesA = ntiles / 2;               // 781
    const int tilesB = ntiles - tilesA;          // 782

    prep_kernel<<<NZ + 1, 256, 0, stream>>>(degi, n, W1, Wt, NZ);
    degrank_gemm1_kernel<<<nDeg + tilesA, 256, 0, stream>>>(
        dst, degi, rank, E, x, Wt, (_Float16*)h1, n, nDeg);
    blocksum_kernel<<<NB, 256, 0, stream>>>(degi, partial, n);
    offsets_kernel<<<NB, 256, 0, stream>>>(degi, partial, rowstart, n, NB);
    fill_gemm1_kernel<<<nFill + tilesB, 256, 0, stream>>>(
        src, dst, rank, dinv, rowstart, csr, E, x, Wt, (_Float16*)h1, n, nFill, tilesA);
    gather64h_kernel<true, true><<<((size_t)n * 8 + 255) / 256, 256, 0, stream>>>(
        h1, csr, rowstart, dinv, b1, out1, n, E);
    gather_gemm2_softmax<<<(n + 63) / 64, 256, 0, stream>>>(
        out1, csr, rowstart, dinv, W2, b2, out, n, E);
}

// Round 16
// 123.038 us; speedup vs baseline: 1.2112x; 1.2112x over previous
//
#include <hip/hip_runtime.h>
#include <hip/hip_fp16.h>
#include <math.h>

// ---------------------------------------------------------------------------
// GCN 2-layer, slab-CSR formulation. Key identity: nrm = dinv[s]*dinv[t]
// factorizes, so aggregation = dinv[t] * sum(g[src]) with g = dinv*h.
// CSR stores ONLY src, in fixed 32-int slabs with the counter in slot 0
// (same cache line as the slots -> one fused atomic+store pass):
//   r = atomicAdd(&hist[dst*32],1); if (r<31) hist[dst*32+1+r] = src
// h1(fp16) = x @ W1 (MFMA, fused into the atomic pass as extra blocks)
// g1 = dinv*h1 (scale pass);  out1 = relu(dinv*(sum g1[src] + g1[t]) + b1)
// g2 = dinv*out1 (folded into gather1 epilogue)
// out = log_softmax( (dinv*(sum g2[src] + g2[t])) @ W2 + b2 )
// ---------------------------------------------------------------------------

typedef _Float16 f16x8 __attribute__((ext_vector_type(8)));
typedef float    f32x4 __attribute__((ext_vector_type(4)));

__global__ void zero_kernel(int4* __restrict__ p, int n4) {
    int i = blockIdx.x * blockDim.x + threadIdx.x;
    if (i < n4) p[i] = make_int4(0, 0, 0, 0);
}

// ---- gemm1 tile body (R12 version): H[tile*64..+64, 0..64](fp16) = X @ W1 ----
static __device__ __forceinline__ void gemm1_tile(const float* __restrict__ X,
                                                  const float* __restrict__ W,
                                                  _Float16* __restrict__ H, int n,
                                                  int tile, _Float16* Ws /*64*128 LDS*/) {
    int t = threadIdx.x;
    int rowbase = tile * 64;

    // stage W transposed: W[k][nn] (row-major 128x64) -> Ws[nn][k], swizzled
    for (int i = t; i < 2048; i += 256) {
        int k = i >> 4;
        int nn0 = (i & 15) * 4;
        float4 v = *reinterpret_cast<const float4*>(W + (size_t)k * 64 + nn0);
        const float* vp = reinterpret_cast<const float*>(&v);
#pragma unroll
        for (int j = 0; j < 4; ++j) {
            int nn = nn0 + j;
            Ws[nn * 128 + (k ^ ((nn & 7) << 3))] = (_Float16)vp[j];
        }
    }

    int w = t >> 6;
    int l = t & 63;
    int lr = l & 15;
    int lk = l >> 4;
    int arow = rowbase + 16 * w + lr;
    int ar = arow < n ? arow : n - 1;

    f16x8 a[4];
#pragma unroll
    for (int kc = 0; kc < 4; ++kc) {
        const float* xp = X + (size_t)ar * 128 + kc * 32 + lk * 8;
        float4 v0 = *reinterpret_cast<const float4*>(xp);
        float4 v1 = *reinterpret_cast<const float4*>(xp + 4);
        f16x8 hv = { (_Float16)v0.x, (_Float16)v0.y, (_Float16)v0.z, (_Float16)v0.w,
                     (_Float16)v1.x, (_Float16)v1.y, (_Float16)v1.z, (_Float16)v1.w };
        a[kc] = hv;
    }
    __syncthreads();

    f32x4 acc[4] = {};
#pragma unroll
    for (int nt = 0; nt < 4; ++nt) {
        int nrow = 16 * nt + lr;
#pragma unroll
        for (int kc = 0; kc < 4; ++kc) {
            int k8 = kc * 32 + lk * 8;
            f16x8 b = *reinterpret_cast<f16x8*>(&Ws[nrow * 128 + (k8 ^ ((nrow & 7) << 3))]);
            acc[nt] = __builtin_amdgcn_mfma_f32_16x16x32_f16(a[kc], b, acc[nt], 0, 0, 0);
        }
    }
    // D: col = lane&15, row = (lane>>4)*4 + reg
#pragma unroll
    for (int nt = 0; nt < 4; ++nt) {
#pragma unroll
        for (int r = 0; r < 4; ++r) {
            int grow = rowbase + 16 * w + lk * 4 + r;
            if (grow < n) H[(size_t)grow * 64 + nt * 16 + lr] = (_Float16)acc[nt][r];
        }
    }
}

// ---- FUSED: slab histogram+fill (blocks < nAF) ∥ gemm1 (all tiles) ----
__global__ __launch_bounds__(256) void fused_af_gemm1(
        const int* __restrict__ src, const int* __restrict__ dst,
        int* __restrict__ hist, int E,
        const float* __restrict__ X, const float* __restrict__ W,
        _Float16* __restrict__ H, int n, int nAF) {
    __shared__ _Float16 Ws[64 * 128];
    int b = blockIdx.x;
    if (b < nAF) {
        int base = b * 1024 + threadIdx.x;
        int d[4], s[4]; bool v[4];
#pragma unroll
        for (int u = 0; u < 4; ++u) {
            int e = base + u * 256;
            v[u] = e < E;
            d[u] = v[u] ? dst[e] : 0;
            s[u] = v[u] ? src[e] : 0;
        }
        int r[4];
#pragma unroll
        for (int u = 0; u < 4; ++u)
            if (v[u]) r[u] = atomicAdd(&hist[d[u] * 32], 1);   // counter in-slab line
#pragma unroll
        for (int u = 0; u < 4; ++u)
            if (v[u] && r[u] < 31) hist[d[u] * 32 + 1 + r[u]] = s[u];  // same line
    } else {
        gemm1_tile(X, W, H, n, b - nAF, Ws);
    }
}

// ---- scale: g1 = dinv * h1 (in place), dinv = rsqrt(deg+1) from slab ----
__global__ __launch_bounds__(256) void scale_kernel(const int* __restrict__ hist,
                                                    __half* __restrict__ H, int n) {
    int gt = blockIdx.x * blockDim.x + threadIdx.x;
    int node = gt >> 3;
    if (node >= n) return;
    int fl = gt & 7;
    float dv = rsqrtf((float)hist[node * 32] + 1.0f);
    __half2 d2 = __float2half2_rn(dv);
    __half2 z  = __float2half2_rn(0.0f);
    float4 raw = reinterpret_cast<float4*>(H)[node * 8 + fl];
    __half2* hp = reinterpret_cast<__half2*>(&raw);
#pragma unroll
    for (int q = 0; q < 4; ++q) hp[q] = __hfma2(hp[q], d2, z);
    reinterpret_cast<float4*>(H)[node * 8 + fl] = raw;
}

// ---- gather1: out1 = relu(dinv*(sum g1[src] + g1[t]) + b1); store g2 = dinv*out1
__global__ __launch_bounds__(256) void gather1_kernel(const __half* __restrict__ G1,
                                                      const int* __restrict__ hist,
                                                      const float* __restrict__ b,
                                                      __half* __restrict__ G2, int n) {
    int gt = blockIdx.x * blockDim.x + threadIdx.x;
    int node = gt >> 3;
    if (node >= n) return;
    int fl = gt & 7;
    const float4* H4 = reinterpret_cast<const float4*>(G1);
    int degt = hist[node * 32];
    float dv = rsqrtf((float)degt + 1.0f);
    int deg = degt < 31 ? degt : 31;
    const int* slots = hist + node * 32 + 1;
    __half2 acc[4];
    __half2 z = __float2half2_rn(0.0f);
#pragma unroll
    for (int q = 0; q < 4; ++q) acc[q] = z;

    for (int r = 0; r < deg; r += 4) {
        int srcr[4]; bool val[4]; float4 raw[4];
#pragma unroll
        for (int u = 0; u < 4; ++u) {
            val[u] = (r + u) < deg;
            srcr[u] = val[u] ? slots[r + u] : node;   // dead slot -> self row (hot)
        }
#pragma unroll
        for (int u = 0; u < 4; ++u)
            raw[u] = H4[srcr[u] * 8 + fl];
#pragma unroll
        for (int u = 0; u < 4; ++u) {
            const __half2* hp = reinterpret_cast<const __half2*>(&raw[u]);
#pragma unroll
            for (int q = 0; q < 4; ++q)
                acc[q] = __hadd2(acc[q], val[u] ? hp[q] : z);
        }
    }
    // self row
    {
        float4 raw = H4[node * 8 + fl];
        const __half2* hp = reinterpret_cast<const __half2*>(&raw);
#pragma unroll
        for (int q = 0; q < 4; ++q) acc[q] = __hadd2(acc[q], hp[q]);
    }
    // epilogue fp32: out = relu(dv*S + b); g2 = dv*out
    float4 bb0 = reinterpret_cast<const float4*>(b)[fl * 2];
    float4 bb1 = reinterpret_cast<const float4*>(b)[fl * 2 + 1];
    float bv[8] = {bb0.x, bb0.y, bb0.z, bb0.w, bb1.x, bb1.y, bb1.z, bb1.w};
    float4 o;
    __half2* op = reinterpret_cast<__half2*>(&o);
#pragma unroll
    for (int q = 0; q < 4; ++q) {
        float2 f = __half22float2(acc[q]);
        float v0 = fmaxf(dv * f.x + bv[2 * q], 0.0f) * dv;
        float v1 = fmaxf(dv * f.y + bv[2 * q + 1], 0.0f) * dv;
        op[q] = __float22half2_rn(make_float2(v0, v1));
    }
    *reinterpret_cast<float4*>(G2 + (size_t)node * 64 + fl * 8) = o;
}

// ---- FUSED: agg2 = dinv*(sum g2[src] + g2[t]) -> log_softmax(agg2 @ W2 + b2)
__global__ __launch_bounds__(256) void gather_gemm2_softmax(
        const __half* __restrict__ G2, const int* __restrict__ hist,
        const float* __restrict__ W, const float* __restrict__ b,
        float* __restrict__ out, int n) {
    constexpr int BM = 64, K = 64, C = 40, XP = 68, HP = 41;
    __shared__ float Xs[BM * XP];
    __shared__ float Ws[K * C];
    __shared__ float bs[C];
    __shared__ float rowm[BM], rowls[BM];
    int t = threadIdx.x;
    int rowbase = blockIdx.x * BM;

    for (int i = t; i < K * C / 4; i += 256)
        ((float4*)Ws)[i] = ((const float4*)W)[i];
    if (t < C) bs[t] = b[t];

    int team = t >> 3, fl = t & 7;
    const float4* H4 = reinterpret_cast<const float4*>(G2);
    __half2 z = __float2half2_rn(0.0f);
#pragma unroll
    for (int pass = 0; pass < 2; ++pass) {
        int lrow = team + pass * 32;
        int node = rowbase + lrow;
        __half2 acc[4];
#pragma unroll
        for (int q = 0; q < 4; ++q) acc[q] = z;
        float dv = 1.0f;
        if (node < n) {
            int degt = hist[node * 32];
            dv = rsqrtf((float)degt + 1.0f);
            int deg = degt < 31 ? degt : 31;
            const int* slots = hist + node * 32 + 1;
            for (int r = 0; r < deg; r += 4) {
                int srcr[4]; bool val[4]; float4 raw[4];
#pragma unroll
                for (int u = 0; u < 4; ++u) {
                    val[u] = (r + u) < deg;
                    srcr[u] = val[u] ? slots[r + u] : node;
                }
#pragma unroll
                for (int u = 0; u < 4; ++u)
                    raw[u] = H4[srcr[u] * 8 + fl];
#pragma unroll
                for (int u = 0; u < 4; ++u) {
                    const __half2* hp = reinterpret_cast<const __half2*>(&raw[u]);
#pragma unroll
                    for (int q = 0; q < 4; ++q)
                        acc[q] = __hadd2(acc[q], val[u] ? hp[q] : z);
                }
            }
            float4 raw = H4[node * 8 + fl];
            const __half2* hp = reinterpret_cast<const __half2*>(&raw);
#pragma unroll
            for (int q = 0; q < 4; ++q) acc[q] = __hadd2(acc[q], hp[q]);
        }
        // agg2 = dv * S (fp32) into the GEMM X-tile
        float* dp = &Xs[lrow * XP + fl * 8];
        float2 f0 = __half22float2(acc[0]), f1 = __half22float2(acc[1]);
        float2 f2 = __half22float2(acc[2]), f3 = __half22float2(acc[3]);
        *reinterpret_cast<float4*>(dp) =
            make_float4(dv * f0.x, dv * f0.y, dv * f1.x, dv * f1.y);
        *reinterpret_cast<float4*>(dp + 4) =
            make_float4(dv * f2.x, dv * f2.y, dv * f3.x, dv * f3.y);
    }
    __syncthreads();

    int tx = t % (C / 4);
    int ty = t / (C / 4);
    bool active = ty < BM / 4;
    float acc[4][4] = {};
    if (active) {
#pragma unroll
        for (int k0 = 0; k0 < K; k0 += 4) {
            float4 xq[4], wq[4];
#pragma unroll
            for (int i = 0; i < 4; ++i)
                xq[i] = *reinterpret_cast<const float4*>(&Xs[(ty * 4 + i) * XP + k0]);
#pragma unroll
            for (int j = 0; j < 4; ++j)
                wq[j] = *reinterpret_cast<const float4*>(&Ws[(k0 + j) * C + tx * 4]);
#pragma unroll
            for (int i = 0; i < 4; ++i) {
                const float* xa = reinterpret_cast<const float*>(&xq[i]);
#pragma unroll
                for (int j = 0; j < 4; ++j) {
                    const float* wb = reinterpret_cast<const float*>(&wq[j]);
                    acc[i][0] += xa[j] * wb[0];
                    acc[i][1] += xa[j] * wb[1];
                    acc[i][2] += xa[j] * wb[2];
                    acc[i][3] += xa[j] * wb[3];
                }
            }
        }
    }
    __syncthreads();
    float* Hs = Xs;
    if (active) {
#pragma unroll
        for (int i = 0; i < 4; ++i) {
            int r = ty * 4 + i;
#pragma unroll
            for (int j = 0; j < 4; ++j)
                Hs[r * HP + tx * 4 + j] = acc[i][j] + bs[tx * 4 + j];
        }
    }
    __syncthreads();
    if (t < BM) {
        float m = -INFINITY;
        for (int j = 0; j < C; ++j) m = fmaxf(m, Hs[t * HP + j]);
        float s = 0.f;
        for (int j = 0; j < C; ++j) s += __expf(Hs[t * HP + j] - m);
        rowm[t] = m; rowls[t] = __logf(s);
    }
    __syncthreads();
    for (int idx = t; idx < BM * C; idx += 256) {
        int r = idx / C, c = idx - r * C;
        int gr = rowbase + r;
        if (gr < n) out[(size_t)gr * C + c] = Hs[r * HP + c] - rowm[r] - rowls[r];
    }
}

extern "C" void kernel_launch(void* const* d_in, const int* in_sizes, int n_in,
                              void* d_out, int out_size, void* d_ws, size_t ws_size,
                              hipStream_t stream) {
    const float* x  = (const float*)d_in[0];
    const int*   ei = (const int*)d_in[1];
    const float* W1 = (const float*)d_in[2];
    const float* b1 = (const float*)d_in[3];
    const float* W2 = (const float*)d_in[4];
    const float* b2 = (const float*)d_in[5];
    float* out = (float*)d_out;

    const int n = in_sizes[0] / 128;   // 100000
    const int E = in_sizes[1] / 2;     // 800000
    const int* src = ei;
    const int* dst = ei + E;

    auto al = [](size_t v) { return (v + 255) & ~(size_t)255; };
    float* ws = (float*)d_ws;
    size_t o_hist = 0;                            // n*32 ints (counter + 31 slots)
    size_t o_h1   = al((size_t)n * 32);           // n*64 halves (h1 -> g1 in place)
    size_t o_g2   = o_h1 + al((size_t)n * 32);    // n*64 halves

    int*    hist = (int*)(ws + o_hist);
    __half* h1   = (__half*)(ws + o_h1);
    __half* g2   = (__half*)(ws + o_g2);

    const int nAF    = (E + 1023) / 1024;         // 782 (4 edges/thread)
    const int ntiles = (n + 63) / 64;             // 1563

    zero_kernel<<<(n * 8 + 255) / 256, 256, 0, stream>>>((int4*)hist, n * 8);
    fused_af_gemm1<<<nAF + ntiles, 256, 0, stream>>>(
        src, dst, hist, E, x, W1, (_Float16*)h1, n, nAF);
    scale_kernel<<<((size_t)n * 8 + 255) / 256, 256, 0, stream>>>(hist, h1, n);
    gather1_kernel<<<((size_t)n * 8 + 255) / 256, 256, 0, stream>>>(
        h1, hist, b1, g2, n);
    gather_gemm2_softmax<<<(n + 63) / 64, 256, 0, stream>>>(
        g2, hist, W2, b2, out, n);
}